// Round 3
// baseline (554.565 us; speedup 1.0000x reference)
//
#include <hip/hip_runtime.h>
#include <hip/hip_fp16.h>
#include <math.h>

#define H 256

typedef _Float16 h2_t __attribute__((ext_vector_type(2)));
union U16x8 { uint4 u; h2_t h[4]; };

// ---- workspace layout (float offsets) ----
#define WS_WTQ   0u           // 196608 f32 (qry_Wih^T, k-major)
#define WS_PT    196608u      // 66560 f32 (posd_W^T)
#define WS_WTPT  263168u      // 98304 f32-equiv = 196608 halves (term Whh packed fp16)
#define WS_WTPC  361472u
#define WS_WTPA  459776u
#define WS_GI_T  558080u      // 20*64*768
#define WS_GI_C  1541120u     // 50*24*768
#define WS_GI_A  2462720u
#define WS_ENC   3384320u     // 64*256
#define WS_HC    3400704u     // 24*256
#define WS_HA    3406848u
#define WS_HCP   3412992u
// end 3419136 floats = 13.7 MB

__device__ __forceinline__ float sigmoidf_(float x){ return 1.f/(1.f+expf(-x)); }

// ---------------- K0: fused weight prep ----------------
// blocks 0..767: pack term Whh -> fp16 [k8][768][8]
// blocks 768..1535: pack doc_c Whh; 1536..2303: pack doc_a Whh
// blocks 2304..2351: transpose qry_Wih [768][256] -> [256][768]
// blocks 2352..2371: transpose posd_W [256][260] -> [260][256]
__global__ __launch_bounds__(256) void k_prep(
    const float* __restrict__ tWhh, const float* __restrict__ cWhh, const float* __restrict__ aWhh,
    const float* __restrict__ qWih, const float* __restrict__ pdW,
    __half* __restrict__ WTPt, __half* __restrict__ WTPc, __half* __restrict__ WTPa,
    float* __restrict__ WTq, float* __restrict__ PT)
{
    const int b = blockIdx.x, tid = threadIdx.x;
    if (b < 2304) {
        const float* in; __half* out; int j;
        if (b < 768)       { in = tWhh; out = WTPt; j = b; }
        else if (b < 1536) { in = cWhh; out = WTPc; j = b - 768; }
        else               { in = aWhh; out = WTPa; j = b - 1536; }
        float v = in[(size_t)j * 256 + tid];
        out[(size_t)(tid >> 3) * 6144 + j * 8 + (tid & 7)] = (__half)v;
        return;
    }
    __shared__ float t[64][65];
    const float* in; float* out; int R, C, bx, by;
    if (b < 2352) { int bb = b - 2304; in = qWih; out = WTq; R = 768; C = 256; bx = bb & 3; by = bb >> 2; }
    else          { int bb = b - 2352; in = pdW;  out = PT;  R = 256; C = 260; bx = bb % 5; by = bb / 5; }
    const int c0 = bx * 64, r0 = by * 64;
    const int cc = tid & 63;
    const int rr = tid >> 6;
#pragma unroll
    for (int s = 0; s < 16; s++) {
        int row = s * 4 + rr;
        if (r0 + row < R && c0 + cc < C)
            t[row][cc] = in[(size_t)(r0 + row) * C + (c0 + cc)];
    }
    __syncthreads();
#pragma unroll
    for (int s = 0; s < 16; s++) {
        int col = s * 4 + rr;
        if (c0 + col < C && r0 + cc < R)
            out[(size_t)(c0 + col) * R + (r0 + cc)] = t[cc][col];
    }
}

// ---------------- K1: gi GEMM (input-side gate preactivations) ----------------
__global__ __launch_bounds__(256) void k_gi_gemm(
    const int* __restrict__ qtok, const int* __restrict__ ptok, const int* __restrict__ ntok,
    const float* __restrict__ temb, const float* __restrict__ demb,
    const float* __restrict__ tWih, const float* __restrict__ cWih, const float* __restrict__ aWih,
    const float* __restrict__ tbih, const float* __restrict__ cbih, const float* __restrict__ abih,
    float* __restrict__ gi_term, float* __restrict__ gi_c, float* __restrict__ gi_a)
{
    __shared__ __align__(16) float As[64][68];
    __shared__ __align__(16) float Bs[64][68];
    __shared__ int tok[64];
    __shared__ int vld[64];

    const int bid = blockIdx.x, tid = threadIdx.x;
    const float *Wih, *bih, *emb; float* out; int nrows, seg, mt, nt;
    if (bid < 240)      { seg = 0; int b = bid;       mt = b / 12; nt = b % 12; Wih = tWih; bih = tbih; emb = temb; out = gi_term; nrows = 1280; }
    else if (bid < 468) { seg = 1; int b = bid - 240; mt = b / 12; nt = b % 12; Wih = cWih; bih = cbih; emb = demb; out = gi_c;    nrows = 1200; }
    else                { seg = 2; int b = bid - 468; mt = b / 12; nt = b % 12; Wih = aWih; bih = abih; emb = demb; out = gi_a;    nrows = 1200; }

    if (tid < 64) {
        int rg = mt * 64 + tid;
        int v = rg < nrows;
        int token = 0;
        if (v) {
            if (seg == 0) { int t = rg >> 6, q = rg & 63; token = qtok[q * 20 + t]; }
            else          { int t = rg / 24, d = rg % 24; token = (d < 12) ? ptok[d * 50 + t] : ntok[(d - 12) * 50 + t]; }
        }
        tok[tid] = token; vld[tid] = v;
    }
    __syncthreads();

    float acc[4][4];
#pragma unroll
    for (int i = 0; i < 4; i++)
#pragma unroll
        for (int jj = 0; jj < 4; jj++) acc[i][jj] = 0.f;

    const int r0 = (tid >> 4) << 2;
    const int j0 = (tid & 15) << 2;
    const int jb = nt * 64;
    const int lr = tid & 15;
    const int lk = (tid >> 4) << 2;

    for (int k0 = 0; k0 < 256; k0 += 64) {
#pragma unroll
        for (int s = 0; s < 4; s++) {
            int r = lr + s * 16;
            float4 v4 = *(const float4*)(emb + (size_t)tok[r] * H + k0 + lk);
            As[lk + 0][r] = v4.x; As[lk + 1][r] = v4.y; As[lk + 2][r] = v4.z; As[lk + 3][r] = v4.w;
            float4 w4 = *(const float4*)(Wih + (size_t)(jb + r) * H + k0 + lk);
            Bs[lk + 0][r] = w4.x; Bs[lk + 1][r] = w4.y; Bs[lk + 2][r] = w4.z; Bs[lk + 3][r] = w4.w;
        }
        __syncthreads();
#pragma unroll 8
        for (int k = 0; k < 64; k++) {
            float4 av = *(const float4*)&As[k][r0];
            float4 bv = *(const float4*)&Bs[k][j0];
            acc[0][0] += av.x * bv.x; acc[0][1] += av.x * bv.y; acc[0][2] += av.x * bv.z; acc[0][3] += av.x * bv.w;
            acc[1][0] += av.y * bv.x; acc[1][1] += av.y * bv.y; acc[1][2] += av.y * bv.z; acc[1][3] += av.y * bv.w;
            acc[2][0] += av.z * bv.x; acc[2][1] += av.z * bv.y; acc[2][2] += av.z * bv.z; acc[2][3] += av.z * bv.w;
            acc[3][0] += av.w * bv.x; acc[3][1] += av.w * bv.y; acc[3][2] += av.w * bv.z; acc[3][3] += av.w * bv.w;
        }
        __syncthreads();
    }

    float4 bias = *(const float4*)(bih + jb + j0);
#pragma unroll
    for (int i = 0; i < 4; i++) {
        int r = r0 + i;
        if (!vld[r]) continue;
        int rg = mt * 64 + r;
        float4 o;
        o.x = acc[i][0] + bias.x; o.y = acc[i][1] + bias.y;
        o.z = acc[i][2] + bias.z; o.w = acc[i][3] + bias.w;
        *(float4*)(out + (size_t)rg * 768 + jb + j0) = o;
    }
}

// ---------------- K2: recurrent scans, 1 chain/block, weights in VGPRs ----------------
// blocks 0..63: term chains (20 steps). 64..87: doc content. 88..111: doc attention (50 steps).
// Thread tid owns Whh rows {tid, tid+256, tid+512} (fp16, 96 uint4 = 384 VGPRs), so the
// GRU update for h[tid] is thread-local. Per step: 1 LDS broadcast read of h + 384 fdot2.
__global__ __launch_bounds__(256, 1) void k_recur3(
    const __half* __restrict__ WTPt, const __half* __restrict__ WTPc, const __half* __restrict__ WTPa,
    const float* __restrict__ tbhh, const float* __restrict__ cbhh, const float* __restrict__ abhh,
    const float* __restrict__ gi_t, const float* __restrict__ gi_c, const float* __restrict__ gi_a,
    float* __restrict__ enc, float* __restrict__ hc, float* __restrict__ ha)
{
    __shared__ __align__(16) __half hhl[H];
    const int b = blockIdx.x, tid = threadIdx.x;
    const __half* WTP; const float *bhh, *gi; float* outp; int T, nch, chain;
    if (b < 64)      { WTP = WTPt; bhh = tbhh; gi = gi_t; T = 20; nch = 64; chain = b;      outp = enc; }
    else if (b < 88) { WTP = WTPc; bhh = cbhh; gi = gi_c; T = 50; nch = 24; chain = b - 64; outp = hc; }
    else             { WTP = WTPa; bhh = abhh; gi = gi_a; T = 50; nch = 24; chain = b - 88; outp = ha; }

    const float br = bhh[tid], bz = bhh[tid + 256], bn = bhh[tid + 512];

    // load this thread's 3 weight rows (fp16) into registers: w[k8*3+r]
    const uint4* __restrict__ W4 = (const uint4*)WTP;
    uint4 w[96];
#pragma unroll
    for (int k8 = 0; k8 < 32; k8++) {
#pragma unroll
        for (int r = 0; r < 3; r++)
            w[k8 * 3 + r] = W4[k8 * 768 + r * 256 + tid];
    }

    float h = 0.f;
    hhl[tid] = (__half)0.f;
    __syncthreads();

    const uint4* hh4 = (const uint4*)hhl;
    for (int t = 0; t < T; t++) {
        const float* __restrict__ grow = gi + (size_t)(t * nch + chain) * 768;
        float gr = grow[tid], gz = grow[tid + 256], gn = grow[tid + 512];

        float acc[3][4];
#pragma unroll
        for (int r = 0; r < 3; r++)
#pragma unroll
            for (int p = 0; p < 4; p++) acc[r][p] = 0.f;

#pragma unroll
        for (int k8 = 0; k8 < 32; k8++) {
            U16x8 hv; hv.u = hh4[k8];
#pragma unroll
            for (int r = 0; r < 3; r++) {
                U16x8 wv; wv.u = w[k8 * 3 + r];
#pragma unroll
                for (int p = 0; p < 4; p++)
                    acc[r][p] = __builtin_amdgcn_fdot2(wv.h[p], hv.h[p], acc[r][p], false);
            }
        }
        float dr = (acc[0][0] + acc[0][1]) + (acc[0][2] + acc[0][3]);
        float dz = (acc[1][0] + acc[1][1]) + (acc[1][2] + acc[1][3]);
        float dn = (acc[2][0] + acc[2][1]) + (acc[2][2] + acc[2][3]);

        float rg = sigmoidf_(gr + br + dr);
        float zg = sigmoidf_(gz + bz + dz);
        float ng = tanhf(gn + rg * (bn + dn));
        h = (1.f - zg) * ng + zg * h;

        __syncthreads();                  // all matvec reads of hhl done
        hhl[tid] = (__half)h;
        __syncthreads();                  // new h visible to all
    }
    outp[(size_t)chain * H + tid] = h;
}

// ---------------- K3: position dense on content vectors ----------------
__global__ __launch_bounds__(256) void k_posd(
    const float* __restrict__ PT, const float* __restrict__ pdb,
    const float* __restrict__ ptab, const float* __restrict__ hc_raw,
    float* __restrict__ hcp)
{
    __shared__ __align__(16) float hl[260];
    const int d = blockIdx.x, j = threadIdx.x;
    if (j < 256) hl[j] = hc_raw[d * H + j];
    if (j < 4)   hl[256 + j] = ptab[(d % 12) * 4 + j];
    __syncthreads();
    float acc = pdb[j];
#pragma unroll 4
    for (int k = 0; k < 260; k++) acc += PT[(size_t)k * 256 + j] * hl[k];
    hcp[d * H + j] = acc;
}

// ---------------- K4: attention + final GRU step (h=0), one block per query ----------------
__global__ __launch_bounds__(256) void k_final(
    const float* __restrict__ enc, const float* __restrict__ ha, const float* __restrict__ hcp,
    const float* __restrict__ WT_q, const float* __restrict__ qbih, const float* __restrict__ qbhh,
    float* __restrict__ out)
{
    __shared__ __align__(16) float ql[H];
    __shared__ float wts[24];
    __shared__ __align__(16) float qs_l[H];
    const int q = blockIdx.x, j = threadIdx.x;
    ql[j] = enc[q * H + j];
    __syncthreads();
    if (j < 192) {
        int dd = j >> 3, l8 = j & 7;
        float s = 0.f;
        for (int k = l8 * 32; k < l8 * 32 + 32; k++) s += ha[dd * H + k] * ql[k];
        s += __shfl_xor(s, 1); s += __shfl_xor(s, 2); s += __shfl_xor(s, 4);
        if (l8 == 0) wts[dd] = s;
    }
    __syncthreads();
    if (j < 2) {
        int base = j * 12;
        float m = wts[base];
        for (int d = 1; d < 12; d++) m = fmaxf(m, wts[base + d]);
        float sum = 0.f;
        for (int d = 0; d < 12; d++) { float e = expf(wts[base + d] - m); wts[base + d] = e; sum += e; }
        float inv = 1.f / sum;
        for (int d = 0; d < 12; d++) wts[base + d] *= inv;
    }
    __syncthreads();
    float qs = ql[j];
#pragma unroll 4
    for (int d = 0; d < 24; d++) qs += wts[d] * hcp[d * H + j];
    qs_l[j] = qs;
    __syncthreads();
    float ar = qbih[j], az = qbih[j + 256], an = qbih[j + 512];
    const float* wp = WT_q + j;
#pragma unroll 4
    for (int k = 0; k < H; k++) {
        float hv = qs_l[k];
        const float* wk = wp + (size_t)k * 768;
        ar += wk[0] * hv; az += wk[256] * hv; an += wk[512] * hv;
    }
    float r = sigmoidf_(ar + qbhh[j]);
    float z = sigmoidf_(az + qbhh[j + 256]);
    float n = tanhf(an + r * qbhh[j + 512]);
    out[q * H + j] = (1.f - z) * n;   // h0 = 0 -> z*h term vanishes
}

extern "C" void kernel_launch(void* const* d_in, const int* in_sizes, int n_in,
                              void* d_out, int out_size, void* d_ws, size_t ws_size,
                              hipStream_t stream)
{
    const int*   qtok = (const int*)d_in[0];
    const int*   ptok = (const int*)d_in[1];
    const int*   ntok = (const int*)d_in[2];
    const float* temb = (const float*)d_in[3];
    const float* tWih = (const float*)d_in[4];
    const float* tWhh = (const float*)d_in[5];
    const float* tbih = (const float*)d_in[6];
    const float* tbhh = (const float*)d_in[7];
    const float* demb = (const float*)d_in[8];
    const float* cWih = (const float*)d_in[9];
    const float* cWhh = (const float*)d_in[10];
    const float* cbih = (const float*)d_in[11];
    const float* cbhh = (const float*)d_in[12];
    const float* aWih = (const float*)d_in[13];
    const float* aWhh = (const float*)d_in[14];
    const float* abih = (const float*)d_in[15];
    const float* abhh = (const float*)d_in[16];
    const float* ptab = (const float*)d_in[17];
    const float* pdW  = (const float*)d_in[18];
    const float* pdb  = (const float*)d_in[19];
    const float* qWih = (const float*)d_in[20];
    const float* qbih = (const float*)d_in[22];
    const float* qbhh = (const float*)d_in[23];

    float* ws  = (float*)d_ws;
    float*  WTq  = ws + WS_WTQ;
    float*  PT   = ws + WS_PT;
    __half* WTPt = (__half*)(ws + WS_WTPT);
    __half* WTPc = (__half*)(ws + WS_WTPC);
    __half* WTPa = (__half*)(ws + WS_WTPA);
    float* GIt = ws + WS_GI_T;
    float* GIc = ws + WS_GI_C;
    float* GIa = ws + WS_GI_A;
    float* ENC = ws + WS_ENC;
    float* HC  = ws + WS_HC;
    float* HA  = ws + WS_HA;
    float* HCP = ws + WS_HCP;

    k_prep<<<2372, 256, 0, stream>>>(tWhh, cWhh, aWhh, qWih, pdW,
                                     WTPt, WTPc, WTPa, WTq, PT);

    k_gi_gemm<<<696, 256, 0, stream>>>(qtok, ptok, ntok, temb, demb,
                                       tWih, cWih, aWih, tbih, cbih, abih,
                                       GIt, GIc, GIa);

    k_recur3<<<112, 256, 0, stream>>>(WTPt, WTPc, WTPa, tbhh, cbhh, abhh,
                                      GIt, GIc, GIa, ENC, HC, HA);

    k_posd<<<24, 256, 0, stream>>>(PT, pdb, ptab, HC, HCP);

    k_final<<<64, 256, 0, stream>>>(ENC, HA, HCP, WTq, qbih, qbhh, (float*)d_out);
}

// Round 4
// 309.078 us; speedup vs baseline: 1.7943x; 1.7943x over previous
//
#include <hip/hip_runtime.h>
#include <hip/hip_fp16.h>
#include <math.h>

#define H 256

typedef _Float16 h2_t __attribute__((ext_vector_type(2)));
union U16x8 { uint4 u; h2_t h[4]; };

// ---- workspace layout (float offsets) ----
#define WS_WTQ   0u           // 196608 f32 (qry_Wih^T, k-major)
#define WS_PT    196608u      // 66560 f32 (posd_W^T)
#define WS_WTPT  263168u      // 98304 f32-equiv = 196608 halves (term Whh packed fp16)
#define WS_WTPC  361472u
#define WS_WTPA  459776u
#define WS_GI_T  558080u      // 20*64*768
#define WS_GI_C  1541120u     // 50*24*768
#define WS_GI_A  2462720u
#define WS_ENC   3384320u     // 64*256
#define WS_HC    3400704u     // 24*256
#define WS_HA    3406848u
#define WS_HCP   3412992u
// end 3419136 floats = 13.7 MB

__device__ __forceinline__ float sigmoidf_(float x){ return 1.f/(1.f+expf(-x)); }

// ---------------- K0: fused weight prep ----------------
// blocks 0..767: pack term Whh -> fp16 [k8][768][8]
// blocks 768..1535: pack doc_c Whh; 1536..2303: pack doc_a Whh
// blocks 2304..2351: transpose qry_Wih [768][256] -> [256][768]
// blocks 2352..2371: transpose posd_W [256][260] -> [260][256]
__global__ __launch_bounds__(256) void k_prep(
    const float* __restrict__ tWhh, const float* __restrict__ cWhh, const float* __restrict__ aWhh,
    const float* __restrict__ qWih, const float* __restrict__ pdW,
    __half* __restrict__ WTPt, __half* __restrict__ WTPc, __half* __restrict__ WTPa,
    float* __restrict__ WTq, float* __restrict__ PT)
{
    const int b = blockIdx.x, tid = threadIdx.x;
    if (b < 2304) {
        const float* in; __half* out; int j;
        if (b < 768)       { in = tWhh; out = WTPt; j = b; }
        else if (b < 1536) { in = cWhh; out = WTPc; j = b - 768; }
        else               { in = aWhh; out = WTPa; j = b - 1536; }
        float v = in[(size_t)j * 256 + tid];
        out[(size_t)(tid >> 3) * 6144 + j * 8 + (tid & 7)] = (__half)v;
        return;
    }
    __shared__ float t[64][65];
    const float* in; float* out; int R, C, bx, by;
    if (b < 2352) { int bb = b - 2304; in = qWih; out = WTq; R = 768; C = 256; bx = bb & 3; by = bb >> 2; }
    else          { int bb = b - 2352; in = pdW;  out = PT;  R = 256; C = 260; bx = bb % 5; by = bb / 5; }
    const int c0 = bx * 64, r0 = by * 64;
    const int cc = tid & 63;
    const int rr = tid >> 6;
#pragma unroll
    for (int s = 0; s < 16; s++) {
        int row = s * 4 + rr;
        if (r0 + row < R && c0 + cc < C)
            t[row][cc] = in[(size_t)(r0 + row) * C + (c0 + cc)];
    }
    __syncthreads();
#pragma unroll
    for (int s = 0; s < 16; s++) {
        int col = s * 4 + rr;
        if (c0 + col < C && r0 + cc < R)
            out[(size_t)(c0 + col) * R + (r0 + cc)] = t[cc][col];
    }
}

// ---------------- K1: gi GEMM (input-side gate preactivations) ----------------
__global__ __launch_bounds__(256) void k_gi_gemm(
    const int* __restrict__ qtok, const int* __restrict__ ptok, const int* __restrict__ ntok,
    const float* __restrict__ temb, const float* __restrict__ demb,
    const float* __restrict__ tWih, const float* __restrict__ cWih, const float* __restrict__ aWih,
    const float* __restrict__ tbih, const float* __restrict__ cbih, const float* __restrict__ abih,
    float* __restrict__ gi_term, float* __restrict__ gi_c, float* __restrict__ gi_a)
{
    __shared__ __align__(16) float As[64][68];
    __shared__ __align__(16) float Bs[64][68];
    __shared__ int tok[64];
    __shared__ int vld[64];

    const int bid = blockIdx.x, tid = threadIdx.x;
    const float *Wih, *bih, *emb; float* out; int nrows, seg, mt, nt;
    if (bid < 240)      { seg = 0; int b = bid;       mt = b / 12; nt = b % 12; Wih = tWih; bih = tbih; emb = temb; out = gi_term; nrows = 1280; }
    else if (bid < 468) { seg = 1; int b = bid - 240; mt = b / 12; nt = b % 12; Wih = cWih; bih = cbih; emb = demb; out = gi_c;    nrows = 1200; }
    else                { seg = 2; int b = bid - 468; mt = b / 12; nt = b % 12; Wih = aWih; bih = abih; emb = demb; out = gi_a;    nrows = 1200; }

    if (tid < 64) {
        int rg = mt * 64 + tid;
        int v = rg < nrows;
        int token = 0;
        if (v) {
            if (seg == 0) { int t = rg >> 6, q = rg & 63; token = qtok[q * 20 + t]; }
            else          { int t = rg / 24, d = rg % 24; token = (d < 12) ? ptok[d * 50 + t] : ntok[(d - 12) * 50 + t]; }
        }
        tok[tid] = token; vld[tid] = v;
    }
    __syncthreads();

    float acc[4][4];
#pragma unroll
    for (int i = 0; i < 4; i++)
#pragma unroll
        for (int jj = 0; jj < 4; jj++) acc[i][jj] = 0.f;

    const int r0 = (tid >> 4) << 2;
    const int j0 = (tid & 15) << 2;
    const int jb = nt * 64;
    const int lr = tid & 15;
    const int lk = (tid >> 4) << 2;

    for (int k0 = 0; k0 < 256; k0 += 64) {
#pragma unroll
        for (int s = 0; s < 4; s++) {
            int r = lr + s * 16;
            float4 v4 = *(const float4*)(emb + (size_t)tok[r] * H + k0 + lk);
            As[lk + 0][r] = v4.x; As[lk + 1][r] = v4.y; As[lk + 2][r] = v4.z; As[lk + 3][r] = v4.w;
            float4 w4 = *(const float4*)(Wih + (size_t)(jb + r) * H + k0 + lk);
            Bs[lk + 0][r] = w4.x; Bs[lk + 1][r] = w4.y; Bs[lk + 2][r] = w4.z; Bs[lk + 3][r] = w4.w;
        }
        __syncthreads();
#pragma unroll 8
        for (int k = 0; k < 64; k++) {
            float4 av = *(const float4*)&As[k][r0];
            float4 bv = *(const float4*)&Bs[k][j0];
            acc[0][0] += av.x * bv.x; acc[0][1] += av.x * bv.y; acc[0][2] += av.x * bv.z; acc[0][3] += av.x * bv.w;
            acc[1][0] += av.y * bv.x; acc[1][1] += av.y * bv.y; acc[1][2] += av.y * bv.z; acc[1][3] += av.y * bv.w;
            acc[2][0] += av.z * bv.x; acc[2][1] += av.z * bv.y; acc[2][2] += av.z * bv.z; acc[2][3] += av.z * bv.w;
            acc[3][0] += av.w * bv.x; acc[3][1] += av.w * bv.y; acc[3][2] += av.w * bv.z; acc[3][3] += av.w * bv.w;
        }
        __syncthreads();
    }

    float4 bias = *(const float4*)(bih + jb + j0);
#pragma unroll
    for (int i = 0; i < 4; i++) {
        int r = r0 + i;
        if (!vld[r]) continue;
        int rg = mt * 64 + r;
        float4 o;
        o.x = acc[i][0] + bias.x; o.y = acc[i][1] + bias.y;
        o.z = acc[i][2] + bias.z; o.w = acc[i][3] + bias.w;
        *(float4*)(out + (size_t)rg * 768 + jb + j0) = o;
    }
}

// ---------------- K2: recurrent scans, 1 chain/block, 768 thr, 1 weight row/thread ----
// blocks 0..63: term chains (20 steps). 64..87: doc content. 88..111: doc attention (50 steps).
// Thread j owns Whh row j as 32 uint4 (128 VGPRs fp16). Per step: uniform LDS broadcast
// of h (fp16), 128 fdot2, gh[j] -> LDS; threads <256 do the GRU update (thread-local j).
__global__ __launch_bounds__(768, 3) void k_recur4(
    const __half* __restrict__ WTPt, const __half* __restrict__ WTPc, const __half* __restrict__ WTPa,
    const float* __restrict__ tbhh, const float* __restrict__ cbhh, const float* __restrict__ abhh,
    const float* __restrict__ gi_t, const float* __restrict__ gi_c, const float* __restrict__ gi_a,
    float* __restrict__ enc, float* __restrict__ hc, float* __restrict__ ha)
{
    __shared__ __align__(16) __half hhl[H];    // current h, fp16
    __shared__ __align__(16) float  gh[768];   // bhh + Whh@h per gate-row
    const int b = blockIdx.x, tid = threadIdx.x;
    const __half* WTP; const float *bhh, *gi; float* outp; int T, nch, chain;
    if (b < 64)      { WTP = WTPt; bhh = tbhh; gi = gi_t; T = 20; nch = 64; chain = b;      outp = enc; }
    else if (b < 88) { WTP = WTPc; bhh = cbhh; gi = gi_c; T = 50; nch = 24; chain = b - 64; outp = hc; }
    else             { WTP = WTPa; bhh = abhh; gi = gi_a; T = 50; nch = 24; chain = b - 88; outp = ha; }

    const float bj = bhh[tid];

    // this thread's weight row (fp16): 32 uint4 = 128 VGPRs, coalesced loads
    const uint4* __restrict__ W4 = (const uint4*)WTP;
    uint4 w[32];
#pragma unroll
    for (int k8 = 0; k8 < 32; k8++) w[k8] = W4[k8 * 768 + tid];

    float h = 0.f;
    if (tid < H) hhl[tid] = (__half)0.f;
    __syncthreads();

    const uint4* hh4 = (const uint4*)hhl;
    const float* __restrict__ grow0 = gi + (size_t)chain * 768;
    const size_t gstride = (size_t)nch * 768;

    for (int t = 0; t < T; t++) {
        // ---- matvec row tid: dot(w[tid][:], h) ----
        float a0 = 0.f, a1 = 0.f, a2 = 0.f, a3 = 0.f;
#pragma unroll
        for (int k8 = 0; k8 < 32; k8++) {
            U16x8 hv; hv.u = hh4[k8];          // wave-uniform broadcast read
            U16x8 wv; wv.u = w[k8];
            a0 = __builtin_amdgcn_fdot2(wv.h[0], hv.h[0], a0, false);
            a1 = __builtin_amdgcn_fdot2(wv.h[1], hv.h[1], a1, false);
            a2 = __builtin_amdgcn_fdot2(wv.h[2], hv.h[2], a2, false);
            a3 = __builtin_amdgcn_fdot2(wv.h[3], hv.h[3], a3, false);
        }
        gh[tid] = bj + ((a0 + a1) + (a2 + a3));
        __syncthreads();

        // ---- GRU update (threads 0..255, thread-local row) ----
        if (tid < H) {
            const float* grow = grow0 + (size_t)t * gstride;
            float r = sigmoidf_(grow[tid]       + gh[tid]);
            float z = sigmoidf_(grow[tid + 256] + gh[tid + 256]);
            float n = tanhf(grow[tid + 512] + r * gh[tid + 512]);
            h = (1.f - z) * n + z * h;
            hhl[tid] = (__half)h;
        }
        __syncthreads();
    }
    if (tid < H) outp[(size_t)chain * H + tid] = h;
}

// ---------------- K3: position dense on content vectors ----------------
__global__ __launch_bounds__(256) void k_posd(
    const float* __restrict__ PT, const float* __restrict__ pdb,
    const float* __restrict__ ptab, const float* __restrict__ hc_raw,
    float* __restrict__ hcp)
{
    __shared__ __align__(16) float hl[260];
    const int d = blockIdx.x, j = threadIdx.x;
    if (j < 256) hl[j] = hc_raw[d * H + j];
    if (j < 4)   hl[256 + j] = ptab[(d % 12) * 4 + j];
    __syncthreads();
    float acc = pdb[j];
#pragma unroll 4
    for (int k = 0; k < 260; k++) acc += PT[(size_t)k * 256 + j] * hl[k];
    hcp[d * H + j] = acc;
}

// ---------------- K4: attention + final GRU step (h=0), one block per query ----------------
__global__ __launch_bounds__(256) void k_final(
    const float* __restrict__ enc, const float* __restrict__ ha, const float* __restrict__ hcp,
    const float* __restrict__ WT_q, const float* __restrict__ qbih, const float* __restrict__ qbhh,
    float* __restrict__ out)
{
    __shared__ __align__(16) float ql[H];
    __shared__ float wts[24];
    __shared__ __align__(16) float qs_l[H];
    const int q = blockIdx.x, j = threadIdx.x;
    ql[j] = enc[q * H + j];
    __syncthreads();
    if (j < 192) {
        int dd = j >> 3, l8 = j & 7;
        float s = 0.f;
        for (int k = l8 * 32; k < l8 * 32 + 32; k++) s += ha[dd * H + k] * ql[k];
        s += __shfl_xor(s, 1); s += __shfl_xor(s, 2); s += __shfl_xor(s, 4);
        if (l8 == 0) wts[dd] = s;
    }
    __syncthreads();
    if (j < 2) {
        int base = j * 12;
        float m = wts[base];
        for (int d = 1; d < 12; d++) m = fmaxf(m, wts[base + d]);
        float sum = 0.f;
        for (int d = 0; d < 12; d++) { float e = expf(wts[base + d] - m); wts[base + d] = e; sum += e; }
        float inv = 1.f / sum;
        for (int d = 0; d < 12; d++) wts[base + d] *= inv;
    }
    __syncthreads();
    float qs = ql[j];
#pragma unroll 4
    for (int d = 0; d < 24; d++) qs += wts[d] * hcp[d * H + j];
    qs_l[j] = qs;
    __syncthreads();
    float ar = qbih[j], az = qbih[j + 256], an = qbih[j + 512];
    const float* wp = WT_q + j;
#pragma unroll 4
    for (int k = 0; k < H; k++) {
        float hv = qs_l[k];
        const float* wk = wp + (size_t)k * 768;
        ar += wk[0] * hv; az += wk[256] * hv; an += wk[512] * hv;
    }
    float r = sigmoidf_(ar + qbhh[j]);
    float z = sigmoidf_(az + qbhh[j + 256]);
    float n = tanhf(an + r * qbhh[j + 512]);
    out[q * H + j] = (1.f - z) * n;   // h0 = 0 -> z*h term vanishes
}

extern "C" void kernel_launch(void* const* d_in, const int* in_sizes, int n_in,
                              void* d_out, int out_size, void* d_ws, size_t ws_size,
                              hipStream_t stream)
{
    const int*   qtok = (const int*)d_in[0];
    const int*   ptok = (const int*)d_in[1];
    const int*   ntok = (const int*)d_in[2];
    const float* temb = (const float*)d_in[3];
    const float* tWih = (const float*)d_in[4];
    const float* tWhh = (const float*)d_in[5];
    const float* tbih = (const float*)d_in[6];
    const float* tbhh = (const float*)d_in[7];
    const float* demb = (const float*)d_in[8];
    const float* cWih = (const float*)d_in[9];
    const float* cWhh = (const float*)d_in[10];
    const float* cbih = (const float*)d_in[11];
    const float* cbhh = (const float*)d_in[12];
    const float* aWih = (const float*)d_in[13];
    const float* aWhh = (const float*)d_in[14];
    const float* abih = (const float*)d_in[15];
    const float* abhh = (const float*)d_in[16];
    const float* ptab = (const float*)d_in[17];
    const float* pdW  = (const float*)d_in[18];
    const float* pdb  = (const float*)d_in[19];
    const float* qWih = (const float*)d_in[20];
    const float* qbih = (const float*)d_in[22];
    const float* qbhh = (const float*)d_in[23];

    float* ws  = (float*)d_ws;
    float*  WTq  = ws + WS_WTQ;
    float*  PT   = ws + WS_PT;
    __half* WTPt = (__half*)(ws + WS_WTPT);
    __half* WTPc = (__half*)(ws + WS_WTPC);
    __half* WTPa = (__half*)(ws + WS_WTPA);
    float* GIt = ws + WS_GI_T;
    float* GIc = ws + WS_GI_C;
    float* GIa = ws + WS_GI_A;
    float* ENC = ws + WS_ENC;
    float* HC  = ws + WS_HC;
    float* HA  = ws + WS_HA;
    float* HCP = ws + WS_HCP;

    k_prep<<<2372, 256, 0, stream>>>(tWhh, cWhh, aWhh, qWih, pdW,
                                     WTPt, WTPc, WTPa, WTq, PT);

    k_gi_gemm<<<696, 256, 0, stream>>>(qtok, ptok, ntok, temb, demb,
                                       tWih, cWih, aWih, tbih, cbih, abih,
                                       GIt, GIc, GIa);

    k_recur4<<<112, 768, 0, stream>>>(WTPt, WTPc, WTPa, tbhh, cbhh, abhh,
                                      GIt, GIc, GIa, ENC, HC, HA);

    k_posd<<<24, 256, 0, stream>>>(PT, pdb, ptab, HC, HCP);

    k_final<<<64, 256, 0, stream>>>(ENC, HA, HCP, WTq, qbih, qbhh, (float*)d_out);
}

// Round 5
// 293.518 us; speedup vs baseline: 1.8894x; 1.0530x over previous
//
#include <hip/hip_runtime.h>
#include <hip/hip_fp16.h>
#include <math.h>

#define H 256

typedef _Float16 f16x8 __attribute__((ext_vector_type(8)));
typedef _Float16 f16x4 __attribute__((ext_vector_type(4)));
typedef float    f32x4 __attribute__((ext_vector_type(4)));
typedef _Float16 h2_t  __attribute__((ext_vector_type(2)));
union U16x8 { uint4 u; h2_t h[4]; };

// ---- workspace layout (float offsets) ----
#define WS_WF_T  0u          // 98304 f32-equiv = 196608 halves (term Whh, MFMA A-frag layout)
#define WS_WF_C  98304u
#define WS_WF_A  196608u
#define WS_W16T  294912u     // flat fp16 [768][256] of term Wih
#define WS_W16C  393216u
#define WS_W16A  491520u
#define WS_W16Q  589824u     // qry Wih fp16 flat
#define WS_PT    688128u     // 66560 f32: posd_W^T [260][256]
#define WS_GI_T  754688u     // 20*64*768 f32
#define WS_GI_C  1737728u    // 50*24*768
#define WS_GI_A  2659328u
#define WS_ENC   3580928u    // 64*256
#define WS_HC    3597312u    // 24*256
#define WS_HA    3603456u    // 24*256
// end 3609600 f32 = 14.44 MB (round-1 used 14.86 MB OK)

__device__ __forceinline__ float sigmoidf_(float x){ return 1.f/(1.f+expf(-x)); }

// ---------------- K0: fused weight prep ----------------
// A) blocks [0,2304): Whh{t,c,a} -> fp16 MFMA A-frag layout.
//    elem i in [0,196608): f=i>>9, lane=(i>>3)&63, e=i&7;
//    row=(f>>3)*16+(lane&15), k=(f&7)*32+((lane>>4)&3)*8+e
// B) blocks [2304,5376): {tWih,cWih,aWih,qWih} f32 -> fp16 flat (same layout)
// C) blocks [5376,5636): posd_W [256][260] -> PT [260][256] f32
__global__ __launch_bounds__(256) void k_prep2(
    const float* __restrict__ tWhh, const float* __restrict__ cWhh, const float* __restrict__ aWhh,
    const float* __restrict__ tWih, const float* __restrict__ cWih, const float* __restrict__ aWih,
    const float* __restrict__ qWih, const float* __restrict__ pdW,
    _Float16* __restrict__ WFt, _Float16* __restrict__ WFc, _Float16* __restrict__ WFa,
    _Float16* __restrict__ W16t, _Float16* __restrict__ W16c, _Float16* __restrict__ W16a,
    _Float16* __restrict__ W16q, float* __restrict__ PT)
{
    const int b = blockIdx.x, tid = threadIdx.x;
    if (b < 2304) {
        int i = b * 256 + tid;               // 0 .. 589823
        int m = i / 196608, r = i % 196608;
        const float* in = (m == 0) ? tWhh : (m == 1) ? cWhh : aWhh;
        _Float16*   out = (m == 0) ? WFt  : (m == 1) ? WFc  : WFa;
        int f = r >> 9, lane = (r >> 3) & 63, e = r & 7;
        int row = (f >> 3) * 16 + (lane & 15);
        int k   = (f & 7) * 32 + ((lane >> 4) & 3) * 8 + e;
        out[r] = (_Float16)in[row * 256 + k];
        return;
    }
    if (b < 5376) {
        int i = (b - 2304) * 256 + tid;      // 0 .. 786431
        int m = i / 196608, r = i % 196608;
        const float* in = (m == 0) ? tWih : (m == 1) ? cWih : (m == 2) ? aWih : qWih;
        _Float16*   out = (m == 0) ? W16t : (m == 1) ? W16c : (m == 2) ? W16a : W16q;
        out[r] = (_Float16)in[r];
        return;
    }
    {
        int i = (b - 5376) * 256 + tid;      // 0 .. 66559
        int k = i >> 8, j = i & 255;
        PT[k * 256 + j] = pdW[j * 260 + k];
    }
}

// ---------------- K1: gi GEMM via MFMA fp16 ----------------
// 64 rows x 64 cols per block, K=256. 4 waves: wave = rowtile.
// A: token embeddings gathered+converted to LDS fp16 [64][264] (pad 8).
// B: Wih fp16 rows straight from global (L2-hot).
__global__ __launch_bounds__(256) void k_gi2(
    const int* __restrict__ qtok, const int* __restrict__ ptok, const int* __restrict__ ntok,
    const float* __restrict__ temb, const float* __restrict__ demb,
    const _Float16* __restrict__ W16t, const _Float16* __restrict__ W16c, const _Float16* __restrict__ W16a,
    const float* __restrict__ tbih, const float* __restrict__ cbih, const float* __restrict__ abih,
    float* __restrict__ git, float* __restrict__ gic, float* __restrict__ gia)
{
    __shared__ __align__(16) _Float16 At[64 * 264];
    __shared__ int tok[64];

    const int bid = blockIdx.x, tid = threadIdx.x;
    const float *emb, *bih; const _Float16* W16; float* out; int nrows, seg, mt, nt;
    if (bid < 240)      { seg = 0; int b = bid;       mt = b / 12; nt = b % 12; emb = temb; W16 = W16t; bih = tbih; out = git; nrows = 1280; }
    else if (bid < 468) { seg = 1; int b = bid - 240; mt = b / 12; nt = b % 12; emb = demb; W16 = W16c; bih = cbih; out = gic; nrows = 1200; }
    else                { seg = 2; int b = bid - 468; mt = b / 12; nt = b % 12; emb = demb; W16 = W16a; bih = abih; out = gia; nrows = 1200; }
    const int rowbase = mt * 64, jb = nt * 64;

    if (tid < 64) {
        int rg = rowbase + tid;
        int token = 0;
        if (rg < nrows) {
            if (seg == 0) { int t = mt, q = tid; token = qtok[q * 20 + t]; }
            else          { int t = rg / 24, d = rg % 24; token = (d < 12) ? ptok[d * 50 + t] : ntok[(d - 12) * 50 + t]; }
        }
        tok[tid] = token;
    }
    __syncthreads();

    // load A-tile: 64 rows x 256 k (f32 -> f16)
#pragma unroll
    for (int i = 0; i < 16; i++) {
        int idx = i * 256 + tid;
        int r = idx >> 6, c4 = idx & 63;
        float4 v = *(const float4*)(emb + (size_t)tok[r] * H + c4 * 4);
        f16x4 hv = { (_Float16)v.x, (_Float16)v.y, (_Float16)v.z, (_Float16)v.w };
        *(f16x4*)(At + r * 264 + c4 * 4) = hv;
    }
    __syncthreads();

    const int wave = tid >> 6, lane = tid & 63;
    const int rt = wave;
    const int kg = (lane >> 4) & 3;

    f16x8 af[8];
    const _Float16* abase = At + (rt * 16 + (lane & 15)) * 264 + kg * 8;
#pragma unroll
    for (int kt = 0; kt < 8; kt++) af[kt] = *(const f16x8*)(abase + kt * 32);

#pragma unroll
    for (int ct = 0; ct < 4; ct++) {
        const int col = jb + ct * 16 + (lane & 15);
        const _Float16* wrow = W16 + (size_t)col * H + kg * 8;
        f32x4 acc = {0.f, 0.f, 0.f, 0.f};
#pragma unroll
        for (int kt = 0; kt < 8; kt++) {
            f16x8 bf = *(const f16x8*)(wrow + kt * 32);
            acc = __builtin_amdgcn_mfma_f32_16x16x32_f16(af[kt], bf, acc, 0, 0, 0);
        }
        float bias = bih[col];
#pragma unroll
        for (int e = 0; e < 4; e++) {
            int row_g = rowbase + rt * 16 + kg * 4 + e;
            if (row_g < nrows)
                out[(size_t)row_g * 768 + col] = acc[e] + bias;
        }
    }
}

// ---------------- K2: recurrent scans via MFMA, weights in register fragments ----
// 112 blocks x 768 thr (12 waves). Wave w owns gate-rows w*64..w*64+63 as 32 A-frags
// (128 VGPRs fp16). Per step: N=1 B-frag of h (masked 4-lane LDS read), 32 mfma/wave,
// gh extracted by 4 lanes/wave to LDS, GRU update in threads<256.
__global__ __launch_bounds__(768) void k_recur5(
    const _Float16* __restrict__ WFt, const _Float16* __restrict__ WFc, const _Float16* __restrict__ WFa,
    const float* __restrict__ tbhh, const float* __restrict__ cbhh, const float* __restrict__ abhh,
    const float* __restrict__ gi_t, const float* __restrict__ gi_c, const float* __restrict__ gi_a,
    float* __restrict__ enc, float* __restrict__ hc, float* __restrict__ ha)
{
    __shared__ __align__(16) _Float16 hhl[H];
    __shared__ __align__(16) float    ghl[768];

    const int b = blockIdx.x, tid = threadIdx.x;
    const _Float16* WF; const float *bhh, *gi; float* outp; int T, nch, chain;
    if (b < 64)      { WF = WFt; bhh = tbhh; gi = gi_t; T = 20; nch = 64; chain = b;      outp = enc; }
    else if (b < 88) { WF = WFc; bhh = cbhh; gi = gi_c; T = 50; nch = 24; chain = b - 64; outp = hc; }
    else             { WF = WFa; bhh = abhh; gi = gi_a; T = 50; nch = 24; chain = b - 88; outp = ha; }

    const int wave = tid >> 6, lane = tid & 63;
    const int grp = (lane >> 4) & 3;          // k-group / row-subgroup
    const bool extr = (lane & 15) == 0;

    // 32 resident A-fragments: frag i=rt*8+kt -> global frag wave*32+i
    const f16x8* __restrict__ WFp = (const f16x8*)WF;
    f16x8 wf[32];
#pragma unroll
    for (int i = 0; i < 32; i++) wf[i] = WFp[(size_t)(wave * 32 + i) * 64 + lane];
    asm volatile("" ::: "memory");   // forbid re-loading WF inside the loop

    float h = 0.f, br = 0.f, bz = 0.f, bn = 0.f;
    if (tid < H) {
        br = bhh[tid]; bz = bhh[tid + 256]; bn = bhh[tid + 512];
        hhl[tid] = (_Float16)0.f;
    }
    __syncthreads();

    for (int t = 0; t < T; t++) {
        f32x4 acc0 = {0.f,0.f,0.f,0.f}, acc1 = {0.f,0.f,0.f,0.f};
        f32x4 acc2 = {0.f,0.f,0.f,0.f}, acc3 = {0.f,0.f,0.f,0.f};
#pragma unroll
        for (int kt = 0; kt < 8; kt++) {
            f16x8 bv = {0,0,0,0,0,0,0,0};
            if (extr) bv = *(const f16x8*)(hhl + kt * 32 + grp * 8);
            acc0 = __builtin_amdgcn_mfma_f32_16x16x32_f16(wf[0 * 8 + kt], bv, acc0, 0, 0, 0);
            acc1 = __builtin_amdgcn_mfma_f32_16x16x32_f16(wf[1 * 8 + kt], bv, acc1, 0, 0, 0);
            acc2 = __builtin_amdgcn_mfma_f32_16x16x32_f16(wf[2 * 8 + kt], bv, acc2, 0, 0, 0);
            acc3 = __builtin_amdgcn_mfma_f32_16x16x32_f16(wf[3 * 8 + kt], bv, acc3, 0, 0, 0);
        }
        if (extr) {
            *(f32x4*)(ghl + wave * 64 +  0 + grp * 4) = acc0;
            *(f32x4*)(ghl + wave * 64 + 16 + grp * 4) = acc1;
            *(f32x4*)(ghl + wave * 64 + 32 + grp * 4) = acc2;
            *(f32x4*)(ghl + wave * 64 + 48 + grp * 4) = acc3;
        }
        __syncthreads();
        if (tid < H) {
            const float* __restrict__ grow = gi + (size_t)(t * nch + chain) * 768;
            float r = sigmoidf_(grow[tid]       + br + ghl[tid]);
            float z = sigmoidf_(grow[tid + 256] + bz + ghl[tid + 256]);
            float n = tanhf(grow[tid + 512] + r * (bn + ghl[tid + 512]));
            h = (1.f - z) * n + z * h;
            hhl[tid] = (_Float16)h;
        }
        __syncthreads();
    }
    if (tid < H) outp[(size_t)chain * H + tid] = h;
}

// ---------------- K3: attention + folded position-dense + final GRU, 1 block/query ----
// attend(posd(hc)) = posd(attend([hc;pe])) since softmax weights sum to 1 per group.
__global__ __launch_bounds__(256) void k_final2(
    const float* __restrict__ enc, const float* __restrict__ ha, const float* __restrict__ hc,
    const float* __restrict__ ptab, const float* __restrict__ PT, const float* __restrict__ pdb,
    const _Float16* __restrict__ qW16, const float* __restrict__ qbih, const float* __restrict__ qbhh,
    float* __restrict__ out)
{
    __shared__ __align__(16) float ql[H];
    __shared__ __align__(16) float csl[H];
    __shared__ float csp[4];
    __shared__ float wts[24];
    __shared__ __align__(16) _Float16 q2h[H];

    const int q = blockIdx.x, j = threadIdx.x;
    ql[j] = enc[q * H + j];
    __syncthreads();

    if (j < 192) {
        int dd = j >> 3, l8 = j & 7;
        float s = 0.f;
        for (int k = l8 * 32; k < l8 * 32 + 32; k++) s += ha[dd * H + k] * ql[k];
        s += __shfl_xor(s, 1); s += __shfl_xor(s, 2); s += __shfl_xor(s, 4);
        if (l8 == 0) wts[dd] = s;
    }
    __syncthreads();
    if (j < 2) {
        int base = j * 12;
        float m = wts[base];
        for (int d = 1; d < 12; d++) m = fmaxf(m, wts[base + d]);
        float sum = 0.f;
        for (int d = 0; d < 12; d++) { float e = expf(wts[base + d] - m); wts[base + d] = e; sum += e; }
        float inv = 1.f / sum;
        for (int d = 0; d < 12; d++) wts[base + d] *= inv;
    }
    __syncthreads();

    // weighted sums of [hc ; pe] over all 24 docs (pos+neg attends combined)
    {
        float cs = 0.f;
#pragma unroll 4
        for (int d = 0; d < 24; d++) cs += wts[d] * hc[d * H + j];
        csl[j] = cs;
    }
    if (j < 4) {
        float cp = 0.f;
        for (int d = 0; d < 24; d++) cp += wts[d] * ptab[(d % 12) * 4 + j];
        csp[j] = cp;
    }
    __syncthreads();

    // position-dense on the attended vector: att = PT^T csum + 2*pdb
    float att = 2.f * pdb[j];
#pragma unroll 4
    for (int k = 0; k < 256; k++) att += csl[k] * PT[(size_t)k * 256 + j];
#pragma unroll
    for (int k = 0; k < 4; k++)   att += csp[k] * PT[(size_t)(256 + k) * 256 + j];

    float q2 = ql[j] + att;
    q2h[j] = (_Float16)q2;
    __syncthreads();

    // final GRU step, h0 = 0: gh = qbhh
    const uint4* q4 = (const uint4*)q2h;
    const uint4* w0 = (const uint4*)(qW16 + (size_t)(j      ) * H);
    const uint4* w1 = (const uint4*)(qW16 + (size_t)(j + 256) * H);
    const uint4* w2 = (const uint4*)(qW16 + (size_t)(j + 512) * H);
    float ar = 0.f, az = 0.f, an = 0.f;
#pragma unroll 8
    for (int k8 = 0; k8 < 32; k8++) {
        U16x8 hv; hv.u = q4[k8];
        U16x8 a; a.u = w0[k8];
        U16x8 bb; bb.u = w1[k8];
        U16x8 c; c.u = w2[k8];
#pragma unroll
        for (int p = 0; p < 4; p++) {
            ar = __builtin_amdgcn_fdot2(a.h[p],  hv.h[p], ar, false);
            az = __builtin_amdgcn_fdot2(bb.h[p], hv.h[p], az, false);
            an = __builtin_amdgcn_fdot2(c.h[p],  hv.h[p], an, false);
        }
    }
    float r = sigmoidf_(ar + qbih[j]       + qbhh[j]);
    float z = sigmoidf_(az + qbih[j + 256] + qbhh[j + 256]);
    float n = tanhf(an + qbih[j + 512] + r * qbhh[j + 512]);
    out[q * H + j] = (1.f - z) * n;
}

extern "C" void kernel_launch(void* const* d_in, const int* in_sizes, int n_in,
                              void* d_out, int out_size, void* d_ws, size_t ws_size,
                              hipStream_t stream)
{
    const int*   qtok = (const int*)d_in[0];
    const int*   ptok = (const int*)d_in[1];
    const int*   ntok = (const int*)d_in[2];
    const float* temb = (const float*)d_in[3];
    const float* tWih = (const float*)d_in[4];
    const float* tWhh = (const float*)d_in[5];
    const float* tbih = (const float*)d_in[6];
    const float* tbhh = (const float*)d_in[7];
    const float* demb = (const float*)d_in[8];
    const float* cWih = (const float*)d_in[9];
    const float* cWhh = (const float*)d_in[10];
    const float* cbih = (const float*)d_in[11];
    const float* cbhh = (const float*)d_in[12];
    const float* aWih = (const float*)d_in[13];
    const float* aWhh = (const float*)d_in[14];
    const float* abih = (const float*)d_in[15];
    const float* abhh = (const float*)d_in[16];
    const float* ptab = (const float*)d_in[17];
    const float* pdW  = (const float*)d_in[18];
    const float* pdb  = (const float*)d_in[19];
    const float* qWih = (const float*)d_in[20];
    const float* qbih = (const float*)d_in[22];
    const float* qbhh = (const float*)d_in[23];

    float* ws = (float*)d_ws;
    _Float16* WFt  = (_Float16*)(ws + WS_WF_T);
    _Float16* WFc  = (_Float16*)(ws + WS_WF_C);
    _Float16* WFa  = (_Float16*)(ws + WS_WF_A);
    _Float16* W16t = (_Float16*)(ws + WS_W16T);
    _Float16* W16c = (_Float16*)(ws + WS_W16C);
    _Float16* W16a = (_Float16*)(ws + WS_W16A);
    _Float16* W16q = (_Float16*)(ws + WS_W16Q);
    float* PT  = ws + WS_PT;
    float* GIt = ws + WS_GI_T;
    float* GIc = ws + WS_GI_C;
    float* GIa = ws + WS_GI_A;
    float* ENC = ws + WS_ENC;
    float* HC  = ws + WS_HC;
    float* HA  = ws + WS_HA;

    k_prep2<<<5636, 256, 0, stream>>>(tWhh, cWhh, aWhh, tWih, cWih, aWih, qWih, pdW,
                                      WFt, WFc, WFa, W16t, W16c, W16a, W16q, PT);

    k_gi2<<<696, 256, 0, stream>>>(qtok, ptok, ntok, temb, demb,
                                   W16t, W16c, W16a, tbih, cbih, abih,
                                   GIt, GIc, GIa);

    k_recur5<<<112, 768, 0, stream>>>(WFt, WFc, WFa, tbhh, cbhh, abhh,
                                      GIt, GIc, GIa, ENC, HC, HA);

    k_final2<<<64, 256, 0, stream>>>(ENC, HA, HC, ptab, PT, pdb,
                                     W16q, qbih, qbhh, (float*)d_out);
}